// Round 8
// baseline (157.340 us; speedup 1.0000x reference)
//
#include <hip/hip_runtime.h>

// SSIM (win=11, sigma=1.5, range=255), N=16 C=3 512x512 fp32 -> [16,502,502].
// R8: granularity attack. R7 evidence: VGPR_Count=76 proves the compiler sank
// the 24-float4 prefetch (needs >=96 VGPR) -- source-level register prefetch
// is unreliable. All pipes <21%, occupancy 23% (~7 of 20 allowed waves/CU),
// only 8 big blocks/CU of work -> supply/granularity is the limiter.
//  - block = 128 threads (2 waves), tile 32x16 -> 8192 blocks (~32/CU work,
//    ~1.5us each); LDS 12.8 kB -> 12 blocks/CU resident (was ~2 effective).
//  - single-band tile: V pass = ONE 16x16x32 MFMA per quantity (K=32 spans
//    all 32 staged H rows; rows 26..31 hit zero band-weights). 15 MFMA per
//    wave-channel vs 25 -- shorter per-wave chain.
//  - no register prefetch (compiler sinks it anyway); latency hidden by TLP.
//  - HPITCH=40 f16 (80 B): col stride 20 dwords covers all 32 banks
//    uniformly for both H-write b64 and V-read b128; 16B-aligned.
//
// MFMA scheme (mfma_f32_16x16x32_f16), B[k][n] = W[k-n] banded, both passes:
//  H: A[m=staged row][k=staged col] -> D[m=row][n=outcol]; C-layout
//     (col=lane&15 -> outcol, row=(lane>>4)*4+reg -> staged row) =>
//     ds_write_b64 transposed into H_T[outcol][row].
//  V: A[m=outcol][k=row] from H_T (k contiguous -> ds_read_b128),
//     D[m=outcol][n=outrow]; same bfrag (banded, zero for k-n>10).
//  x^2/y^2/xy A-frags derived in registers (v_pk_mul_f16 of x/y frags).
// Edge clamps (uniform min()): clamped staged rows/cols feed only zero
// band-weights (k-n>10 for all valid n) or store-masked outputs.

namespace {

constexpr int NN = 16, CC = 3, HH = 512, WW = 512;
constexpr int OH = HH - 10, OW = WW - 10;          // 502 x 502
constexpr int TW = 32, TH = 16;                    // output tile per block
constexpr int HPITCH = 40;                         // H_T k-pitch (f16)
constexpr float C1c = 6.5025f;                     // (0.01*255)^2
constexpr float C2c = 58.5225f;                    // (0.03*255)^2

typedef _Float16 half8   __attribute__((ext_vector_type(8)));
typedef _Float16 half4   __attribute__((ext_vector_type(4)));
typedef float    floatv4 __attribute__((ext_vector_type(4)));

__device__ const float WF[11] = {
    0.00102838f, 0.00759876f, 0.03600077f, 0.10936069f, 0.21300553f,
    0.26601172f,
    0.21300553f, 0.10936069f, 0.03600077f, 0.00759876f, 0.00102838f
};

__device__ inline half8 pack8(const float4& a, const float4& b) {
    half8 h = {(_Float16)a.x, (_Float16)a.y, (_Float16)a.z, (_Float16)a.w,
               (_Float16)b.x, (_Float16)b.y, (_Float16)b.z, (_Float16)b.w};
    return h;
}

__global__ __launch_bounds__(128, 2)
void ssim_kernel(const float* __restrict__ X, const float* __restrict__ Y,
                 float* __restrict__ out)
{
    __shared__ __align__(16) _Float16 s_ht[5][TW][HPITCH];  // 12800 B
    __shared__ _Float16 s_wtab[16];

    const int tid  = threadIdx.x;
    const int lane = tid & 63;
    const int wvc  = tid >> 6;          // wave id = outcol chunk (16 cols)
    const int col0 = blockIdx.x * TW + wvc * 16;   // this wave's col base
    const int row0 = blockIdx.y * TH;
    const int n    = blockIdx.z;

    if (tid < 16) s_wtab[tid] = (tid < 11) ? (_Float16)WF[tid] : (_Float16)0.f;
    __syncthreads();   // only block-wide sync in the kernel

    // banded weight fragment B[k][n] = W[k-n]; lane: n=lane&15, k=(lane>>4)*8+j
    half8 bfrag;
    {
        const int bn = lane & 15, kq = (lane >> 4) * 8;
        #pragma unroll
        for (int j = 0; j < 8; ++j) {
            int kk = kq + j - bn;
            kk = (kk < 0 || kk > 10) ? 11 : kk;   // index 11 holds 0
            bfrag[j] = s_wtab[kk];
        }
    }

    const int arow = lane & 15;          // A m-select (row for H, outcol for V)
    const int aq   = lane >> 4;          // A k-quad / C row-group

    // global addresses (uniform clamps; clamped data feeds only zero-weight
    // taps or store-masked outputs)
    int gcol = col0 + aq * 8;
    gcol = gcol <= WW - 8 ? gcol : WW - 8;
    int grow[2];
    #pragma unroll
    for (int rc = 0; rc < 2; ++rc) {
        int g = row0 + rc * 16 + arow;
        grow[rc] = g < HH ? g : HH - 1;
    }

    float acc[4] = {0.f, 0.f, 0.f, 0.f};

    const size_t plane = (size_t)HH * WW;
    const float* Xn = X + (size_t)n * CC * plane;
    const float* Yn = Y + (size_t)n * CC * plane;
    const floatv4 zf = {0.f, 0.f, 0.f, 0.f};

    #pragma unroll
    for (int ch = 0; ch < CC; ++ch) {
        const float* Xc = Xn + (size_t)ch * plane;
        const float* Yc = Yn + (size_t)ch * plane;

        // ---- 8 dwordx4 loads: 2 rc x 8-col chunk for x and y ----
        half8 axf[2], ayf[2];
        #pragma unroll
        for (int rc = 0; rc < 2; ++rc) {
            const float* bx = Xc + (size_t)grow[rc] * WW + gcol;
            const float* by = Yc + (size_t)grow[rc] * WW + gcol;
            float4 x0 = *(const float4*)bx;
            float4 x1 = *(const float4*)(bx + 4);
            float4 y0 = *(const float4*)by;
            float4 y1 = *(const float4*)(by + 4);
            axf[rc] = pack8(x0, x1);
            ayf[rc] = pack8(y0, y1);
        }

        // ---- H phase: 10 MFMAs + 10 ds_write_b64 (batched) ----
        #pragma unroll
        for (int q = 0; q < 5; ++q) {
            #pragma unroll
            for (int rc = 0; rc < 2; ++rc) {
                half8 a;
                if      (q == 0) a = axf[rc];
                else if (q == 1) a = ayf[rc];
                else if (q == 2) a = axf[rc] * axf[rc];
                else if (q == 3) a = ayf[rc] * ayf[rc];
                else             a = axf[rc] * ayf[rc];
                floatv4 d = __builtin_amdgcn_mfma_f32_16x16x32_f16(
                    a, bfrag, zf, 0, 0, 0);
                half4 h = {(_Float16)d[0], (_Float16)d[1],
                           (_Float16)d[2], (_Float16)d[3]};
                // transposed store: [outcol][staged row]
                *(half4*)&s_ht[q][wvc*16 + arow][rc*16 + aq*4] = h;
            }
        }

        // ---- V phase: 5 ds_read_b128 + 5 MFMAs (K=32 spans the band) ----
        floatv4 vf[5];
        #pragma unroll
        for (int q = 0; q < 5; ++q) {
            half8 av = *(const half8*)&s_ht[q][wvc*16 + arow][aq*8];
            vf[q] = __builtin_amdgcn_mfma_f32_16x16x32_f16(
                av, bfrag, zf, 0, 0, 0);
        }

        // ---- SSIM ----
        #pragma unroll
        for (int p = 0; p < 4; ++p) {
            float m1 = vf[0][p], m2 = vf[1][p];
            float exx = vf[2][p], eyy = vf[3][p], exy = vf[4][p];
            float m1s = m1*m1, m2s = m2*m2, m12 = m1*m2;
            float s1 = exx - m1s, s2 = eyy - m2s, s12 = exy - m12;
            float n1 = 2.f*m12 + C1c, d1 = m1s + m2s + C1c;
            float n2 = 2.f*s12 + C2c, d2 = s1 + s2 + C2c;
            acc[p] = fmaf(n1 * n2, __builtin_amdgcn_rcpf(d1 * d2), acc[p]);
        }
    }

    // ---- epilogue: 1 - mean over channels ----
    // V C-layout: lane holds outrow = lane&15 (=arow), outcols aq*4 + p
    const int orow = row0 + arow;
    const int ocol = col0 + aq * 4;
    if (orow < OH) {
        float r0v = 1.f - acc[0] * (1.f/3.f);
        float r1v = 1.f - acc[1] * (1.f/3.f);
        float r2v = 1.f - acc[2] * (1.f/3.f);
        float r3v = 1.f - acc[3] * (1.f/3.f);
        size_t base = ((size_t)n * OH + orow) * OW + ocol;
        if (ocol + 3 < OW) {
            *(float2*)(out + base)     = make_float2(r0v, r1v);
            *(float2*)(out + base + 2) = make_float2(r2v, r3v);
        } else {
            float rs[4] = {r0v, r1v, r2v, r3v};
            #pragma unroll
            for (int p = 0; p < 4; ++p)
                if (ocol + p < OW) out[base + p] = rs[p];
        }
    }
}

} // namespace

extern "C" void kernel_launch(void* const* d_in, const int* in_sizes, int n_in,
                              void* d_out, int out_size, void* d_ws, size_t ws_size,
                              hipStream_t stream) {
    const float* X = (const float*)d_in[0];
    const float* Y = (const float*)d_in[1];
    float* out = (float*)d_out;

    dim3 grid((OW + TW - 1) / TW,   // 16
              (OH + TH - 1) / TH,   // 32
              NN);                  // 16
    ssim_kernel<<<grid, 128, 0, stream>>>(X, Y, out);
}